// Round 8
// baseline (205.569 us; speedup 1.0000x reference)
//
#include <hip/hip_runtime.h>
#include <math.h>

#define NB 32              // batch
#define HW (1024 * 1024)   // pixels per image
#define BINS 64            // MAX_INST
#define KLBL 64            // labels per image
#define NCLS 8             // lesion classes
#define BPI 64             // blocks per image for histogram
#define TPB 256
#define CHUNK4 4096        // int4 per block chunk (64 KB contiguous)

// ---------------------------------------------------------------------------
// Histogram (round-5 structure = best so far) with PARTIAL-SUM output:
// each block plain-stores its 64 block-local bin counts to a private row of
// hist_part[2048][64]. Every slot is written every launch -> no memset
// dispatch needed (d_ws 0xAA poison harmless), no global atomics, no
// atomic-drain at block exit. XCD remap reverted (r7: neutral).
// ---------------------------------------------------------------------------
__global__ __launch_bounds__(TPB) void hist_kernel(const int* __restrict__ mask,
                                                   int* __restrict__ hist_part) {
    __shared__ int sh[4][BINS];
    const int tid = threadIdx.x;
    const int wave = tid >> 6;
    const int b = blockIdx.x / BPI;
    const int part = blockIdx.x % BPI;

    sh[tid >> 6][tid & 63] = 0;   // 256 threads cover 4*64
    __syncthreads();

    const int4* __restrict__ p4 =
        (const int4*)(mask + (size_t)b * HW) + (size_t)part * CHUNK4;

    #pragma unroll
    for (int h = 0; h < 2; ++h) {
        int4 v[8];
        #pragma unroll
        for (int k = 0; k < 8; ++k)
            v[k] = p4[(h * 8 + k) * TPB + tid];   // wave req k: 4 KB apart, dense
        #pragma unroll
        for (int k = 0; k < 8; ++k) {
            atomicAdd(&sh[wave][v[k].x & 63], 1);
            atomicAdd(&sh[wave][v[k].y & 63], 1);
            atomicAdd(&sh[wave][v[k].z & 63], 1);
            atomicAdd(&sh[wave][v[k].w & 63], 1);
        }
    }
    __syncthreads();

    if (tid < BINS) {
        int s = sh[0][tid] + sh[1][tid] + sh[2][tid] + sh[3][tid];
        hist_part[blockIdx.x * BINS + tid] = s;   // plain coalesced store
    }
}

// ---------------------------------------------------------------------------
// Finalize: stage A reduces 64 partials per (b,bin) into LDS (coalesced,
// independent loads); stage B gathers sizes via label_gt (int32 pairs),
// scatters into per-class counts, clamp/100, BCE-with-logits, mean -> out[0].
// ---------------------------------------------------------------------------
__global__ __launch_bounds__(TPB) void finalize_kernel(const float* __restrict__ pred,
                                                       const int* __restrict__ lg,
                                                       const int* __restrict__ hist_part,
                                                       float* __restrict__ out) {
    __shared__ int shist[NB * BINS];    // 8 KB
    __shared__ float cnts[NB * NCLS];
    __shared__ float wsum[4];
    const int tid = threadIdx.x;

    // Stage A: 2048 (b,bin) sums / 256 threads = 8 each; lanes of a wave hit
    // contiguous 256 B per q-step (coalesced), 64 independent loads per sum.
    for (int i = tid; i < NB * BINS; i += TPB) {
        const int* p = hist_part + (i >> 6) * (BPI * BINS) + (i & 63);
        int s = 0;
        #pragma unroll
        for (int q = 0; q < BPI; ++q) s += p[q * BINS];
        shist[i] = s;
    }
    cnts[tid] = 0.0f;
    __syncthreads();

    // Stage B: B*K = 2048 entries; 8 per thread.
    for (int e = tid; e < NB * KLBL; e += TPB) {
        int inst  = lg[e * 2 + 0];
        int label = lg[e * 2 + 1];
        if (label > 0 && label <= NCLS) {
            float sz = (float)shist[(e >> 6) * BINS + (inst & 63)];
            atomicAdd(&cnts[(e >> 6) * NCLS + (label - 1)], sz);
        }
    }
    __syncthreads();

    float x = pred[tid];
    float t = fminf(cnts[tid] * (1.0f / 100.0f), 1.0f);
    float l = fmaxf(x, 0.0f) - x * t + log1pf(expf(-fabsf(x)));

    for (int off = 32; off > 0; off >>= 1)
        l += __shfl_down(l, off, 64);
    if ((tid & 63) == 0) wsum[tid >> 6] = l;
    __syncthreads();
    if (tid == 0)
        out[0] = (wsum[0] + wsum[1] + wsum[2] + wsum[3]) * (1.0f / (NB * NCLS));
}

extern "C" void kernel_launch(void* const* d_in, const int* in_sizes, int n_in,
                              void* d_out, int out_size, void* d_ws, size_t ws_size,
                              hipStream_t stream) {
    const float* pred = (const float*)d_in[0];    // [32, 8] fp32
    const int*   mask = (const int*)d_in[1];      // [32, 1024, 1024] int32
    const int*   lg   = (const int*)d_in[2];      // [32, 64, 2] delivered as int32
    float* out = (float*)d_out;
    int* hist_part = (int*)d_ws;                  // [2048][64] int32 = 512 KB

    hist_kernel<<<NB * BPI, TPB, 0, stream>>>(mask, hist_part);
    finalize_kernel<<<1, TPB, 0, stream>>>(pred, lg, hist_part, out);
}